// Round 3
// baseline (659.918 us; speedup 1.0000x reference)
//
#include <hip/hip_runtime.h>
#include <cstdint>
#include <cstddef>

typedef float f32x4 __attribute__((ext_vector_type(4)));
typedef __bf16 bf16x8 __attribute__((ext_vector_type(8)));
typedef unsigned short u16;

__device__ __forceinline__ float bf2f(u16 u) {
  union { unsigned int i; float f; } x; x.i = ((unsigned int)u) << 16; return x.f;
}
__device__ __forceinline__ u16 f2bf(float f) {
  union { float f; unsigned int i; } x; x.f = f;
  unsigned int i = x.i;
  i += 0x7fffu + ((i >> 16) & 1u);   // round-to-nearest-even
  return (u16)(i >> 16);
}

#if defined(__has_builtin)
#if __has_builtin(__builtin_amdgcn_global_load_lds)
#define HAS_GLL 1
#endif
#endif

__device__ __forceinline__ void async16(const u16* g, u16* l) {
#ifdef HAS_GLL
  __builtin_amdgcn_global_load_lds((const __attribute__((address_space(1))) void*)(const void*)g,
                                   (__attribute__((address_space(3))) void*)(void*)l, 16, 0, 0);
#else
  *(uint4*)l = *(const uint4*)g;
#endif
}

// ---------------- mask compaction (dtype-width-agnostic) ----------------
__global__ void compact_mask(const unsigned char* __restrict__ mask,
                             int* __restrict__ padIdx, int* __restrict__ padCnt,
                             float* __restrict__ maskf) {
  const int b = blockIdx.x;        // 4 rows
  const int lane = threadIdx.x;    // 64
  int stride = 1;
  if (mask[1] == 0) stride = (mask[4] != 0) ? 4 : 8;
  int cnt = 0;
  for (int s0 = 0; s0 < 1024; s0 += 64) {
    const int s = s0 + lane;
    const bool valid = (mask[(size_t)((b << 10) + s) * stride] != 0);
    maskf[(b << 10) + s] = valid ? 1.f : 0.f;
    const bool pad = !valid;
    const unsigned long long bal = __ballot(pad);
    const int rank = (int)__popcll(bal & ((1ull << lane) - 1ull));
    if (pad) padIdx[(b << 10) + cnt + rank] = s;
    cnt += (int)__popcll(bal);
  }
  if (lane == 0) padCnt[b] = cnt;
}

// ---------------- fp32 -> bf16 convert ----------------
__global__ __launch_bounds__(256)
void f32_to_bf16(const float* __restrict__ in, u16* __restrict__ out, int n4) {
  const int i = blockIdx.x * 256 + threadIdx.x;
  if (i < n4) {
    const float4 v = ((const float4*)in)[i];
    u16 o[4] = { f2bf(v.x), f2bf(v.y), f2bf(v.z), f2bf(v.w) };
    ((ushort4*)out)[i] = *(const ushort4*)o;
  }
}

// ---------------- fp32 transpose+convert: in[R][C] f32 -> out[C][R] bf16 ----------------
__global__ __launch_bounds__(256)
void transpose_f32_bf16(const float* __restrict__ in, u16* __restrict__ out, int R, int C) {
  __shared__ u16 tile[64][65];
  const int r0 = blockIdx.y << 6, c0 = blockIdx.x << 6;
  const int tid = threadIdx.x;
  const int lr = tid >> 3, lc = (tid & 7) << 3;
#pragma unroll
  for (int p = 0; p < 2; ++p) {
    const int row = lr + (p << 5);
    const float4 a = *(const float4*)(in + (size_t)(r0 + row) * C + c0 + lc);
    const float4 bq = *(const float4*)(in + (size_t)(r0 + row) * C + c0 + lc + 4);
    tile[row][lc + 0] = f2bf(a.x); tile[row][lc + 1] = f2bf(a.y);
    tile[row][lc + 2] = f2bf(a.z); tile[row][lc + 3] = f2bf(a.w);
    tile[row][lc + 4] = f2bf(bq.x); tile[row][lc + 5] = f2bf(bq.y);
    tile[row][lc + 6] = f2bf(bq.z); tile[row][lc + 7] = f2bf(bq.w);
  }
  __syncthreads();
#pragma unroll
  for (int p = 0; p < 2; ++p) {
    const int oc = lr + (p << 5);
    u16 tmp[8];
#pragma unroll
    for (int e = 0; e < 8; ++e) tmp[e] = tile[lc + e][oc];
    *(uint4*)(out + (size_t)(c0 + oc) * R + r0 + lc) = *(const uint4*)tmp;
  }
}

// ---------------- legacy 128x128 GEMM (kept for the small atto matmul) ----------------
template<int NTAPS, bool RELU, int SPLITK, int KORIG, int NBN>
__global__ __launch_bounds__(256)
void gemm_bt(const u16* __restrict__ A, const u16* __restrict__ BT,
             const float* __restrict__ bias, u16* __restrict__ C, u16* __restrict__ Calt,
             int M, int N, const u16* __restrict__ zp) {
  __shared__ __align__(16) u16 As[128 * 64];
  __shared__ __align__(16) u16 Bs[128 * 64];
  const int tid = threadIdx.x;
  const int id = blockIdx.x + NBN * blockIdx.y;
  const int bm = ((id / (16 * NBN)) << 4) + (id & 15);
  const int bn = (id % (16 * NBN)) >> 4;
  const int m0 = bm << 7;
  const int n0 = bn << 7;
  const int kz = (SPLITK > 1) ? blockIdx.z : 0;
  constexpr int Ktot = NTAPS * KORIG;
  constexpr int kchunk = Ktot / SPLITK;
  const int lane = tid & 63;
  const int w = tid >> 6;
  const int wm = (w >> 1) << 6;
  const int wn = (w & 1) << 6;
  const int fr = lane & 15;
  const int quad = lane >> 4;
  const int srow = tid >> 3;
  const int scol = (tid & 7) << 3;
  const int sx = (((tid & 7) ^ (srow & 7)) << 3);

  f32x4 acc[4][4] = {};

  const int kbeg = kz * kchunk, kend = kbeg + kchunk;
  int k = kbeg;
  while (k < kend) {
    const int t = (NTAPS == 3) ? (k / KORIG) : 0;
    const int seg_end = (NTAPS == 3) ? min(kend, (t + 1) * KORIG) : kend;
    const int c0 = k - t * KORIG;
    const u16* aptr[4];
    const u16* bptr[4];
#pragma unroll
    for (int i = 0; i < 4; ++i) {
      const int row = srow + (i << 5);
      if (NTAPS == 3) {
        const int m = m0 + row;
        const int sp = (m & 1023) + t - 1;
        aptr[i] = ((unsigned)sp < 1024u) ? (A + (size_t)(m + t - 1) * KORIG + c0 + sx)
                                         : (zp + ((tid & 255) << 3));
      } else {
        aptr[i] = A + (size_t)(m0 + row) * KORIG + k + sx;
      }
      bptr[i] = BT + (size_t)(n0 + row) * Ktot + k + sx;
    }
    for (; k < seg_end; k += 64) {
#pragma unroll
      for (int i = 0; i < 4; ++i) {
        const int row = srow + (i << 5);
        async16(aptr[i], &As[(row << 6) + scol]);
        async16(bptr[i], &Bs[(row << 6) + scol]);
        aptr[i] += 64; bptr[i] += 64;
      }
      asm volatile("s_waitcnt vmcnt(0)" ::: "memory");
      __syncthreads();
#pragma unroll
      for (int ks = 0; ks < 64; ks += 32) {
        const int ccol = ((((ks >> 3) + quad) ^ (fr & 7)) << 3);
        bf16x8 af[4], bfr[4];
#pragma unroll
        for (int mi = 0; mi < 4; ++mi)
          af[mi] = *(const bf16x8*)&As[((wm + (mi << 4) + fr) << 6) + ccol];
#pragma unroll
        for (int ni = 0; ni < 4; ++ni)
          bfr[ni] = *(const bf16x8*)&Bs[((wn + (ni << 4) + fr) << 6) + ccol];
#pragma unroll
        for (int mi = 0; mi < 4; ++mi)
#pragma unroll
          for (int ni = 0; ni < 4; ++ni)
            acc[mi][ni] = __builtin_amdgcn_mfma_f32_16x16x32_bf16(af[mi], bfr[ni], acc[mi][ni], 0, 0, 0);
      }
      __syncthreads();
    }
  }
  const int rbase = m0 + wm + (quad << 2);
  const int cbase = n0 + wn + fr;
  u16* dst = C;
  if (SPLITK > 1 && kz > 0) dst = Calt + (size_t)(kz - 1) * ((size_t)M * N);
#pragma unroll
  for (int ni = 0; ni < 4; ++ni) {
    const int col = cbase + (ni << 4);
    const float bv = (SPLITK == 1 && bias) ? bias[col] : 0.f;
#pragma unroll
    for (int mi = 0; mi < 4; ++mi) {
#pragma unroll
      for (int r = 0; r < 4; ++r) {
        float v = acc[mi][ni][r] + bv;
        if (RELU) v = fmaxf(v, 0.f);
        dst[(size_t)(rbase + (mi << 4) + r) * N + col] = f2bf(v);
      }
    }
  }
}

// ---------------- 256x256 GEMM, read-ahead pipelined (T3+T4-lgkm+T5) ----------------
// 8 waves (2M x 4N), BK=64. LDS slots: As[(t&1)*2+mh], Bs[(t&1)*2+nh] (128x64 each).
// Phases per K-tile = (mh,ks) slices; each phase issues the NEXT phase's ds_reads,
// then a COUNTED lgkmcnt leaves them in flight while MFMA'ing on frags read last
// phase (the m201 "derived waits" mechanism: LDS drain overlaps MFMA).
// Per-tile reads 8/4/4/8; frag regs: afC/afN (16 each) + bfk[2][2][2] (32) = 64.
// Ledger: lgkm counts = reads issued this phase (8/4/4/8). Stages: all 4 halves of
// t+1 issued at ph0(t), retired by WAITV(0)+BAR at end-ph2(t) (2.5-phase cover).
// Slot recycle: last reads of t-1 slots issued ph2(t-1) are drained by ph3(t-1)'s
// lgkm(8) before the end-ph3 barrier; ph0(t) staging is after it -> safe.
#define BAR8() do { asm volatile("" ::: "memory"); __builtin_amdgcn_s_barrier(); asm volatile("" ::: "memory"); } while (0)
#define WAITV(N) asm volatile("s_waitcnt vmcnt(" #N ")" ::: "memory")
#define LGKM(N) asm volatile("s_waitcnt lgkmcnt(" #N ")" ::: "memory")
#define SB0() __builtin_amdgcn_sched_barrier(0)

#define READ_AF(DST, SLOT, KS) \
  _Pragma("unroll") for (int mi = 0; mi < 4; ++mi) \
    DST[mi] = *(const bf16x8*)&As[SLOT][((wm + (mi << 4) + fr) << 6) + (((((KS) << 2) + quad) ^ (fr & 7)) << 3)];
#define READ_BF(KS, SP) \
  _Pragma("unroll") for (int nh = 0; nh < 2; ++nh) \
  _Pragma("unroll") for (int ni = 0; ni < 2; ++ni) \
    bfk[KS][nh][ni] = *(const bf16x8*)&Bs[(SP) | nh][((wn + (ni << 4) + fr) << 6) + (((((KS) << 2) + quad) ^ (fr & 7)) << 3)];
#define MFMA_P(MH, AF, KS) \
  __builtin_amdgcn_s_setprio(1); \
  _Pragma("unroll") for (int mi = 0; mi < 4; ++mi) \
  _Pragma("unroll") for (int nh = 0; nh < 2; ++nh) \
  _Pragma("unroll") for (int ni = 0; ni < 2; ++ni) \
    acc[MH][mi][nh][ni] = __builtin_amdgcn_mfma_f32_16x16x32_bf16(AF[mi], bfk[KS][nh][ni], acc[MH][mi][nh][ni], 0, 0, 0); \
  __builtin_amdgcn_s_setprio(0)

template<int NTAPS, bool RELU, int SPLITK, int KORIG>
__global__ __launch_bounds__(512, 2)
void gemm8(const u16* __restrict__ A, const u16* __restrict__ BT,
           const float* __restrict__ bias, u16* __restrict__ C, u16* __restrict__ Calt,
           int M, int N, const u16* __restrict__ zp) {
  __shared__ __align__(16) u16 As[4][128 * 64];   // 64 KB
  __shared__ __align__(16) u16 Bs[4][128 * 64];   // 64 KB
  constexpr int Ktot = NTAPS * KORIG;
  constexpr int kchunk = Ktot / SPLITK;
  constexpr int NT = kchunk / 64;
  const int tid = threadIdx.x;
  const int id = blockIdx.x;
  const int bm = id & 15, bn = id >> 4;
  const int m0 = bm << 8, n0 = bn << 8;
  const int kz = (SPLITK > 1) ? blockIdx.z : 0;
  const int kbeg = kz * kchunk;
  const int lane = tid & 63, w = tid >> 6;
  const int wm = (w >> 2) << 6;       // within-half M base (0/64)
  const int wn = (w & 3) << 5;        // within-half N base (0/32/64/96)
  const int fr = lane & 15, quad = lane >> 4;
  const int srow = tid >> 3;          // 0..63
  const int scol = (tid & 7) << 3;    // linear LDS dest col (dest = base + 16B*lane)
  const int sx = (((tid & 7) ^ (srow & 7)) << 3);   // swizzled global src col

  // persistent B staging pointers (advance +64/tile)
  const u16* bp[2][2];
#pragma unroll
  for (int nh = 0; nh < 2; ++nh)
#pragma unroll
    for (int j = 0; j < 2; ++j)
      bp[nh][j] = BT + (size_t)(n0 + (nh << 7) + srow + (j << 6)) * Ktot + kbeg + sx;

  auto stageA = [&](int ts, int mh) {
    const int k = kbeg + (ts << 6);
    const int tap = (NTAPS == 3) ? (k / KORIG) : 0;
    const int c0 = k - tap * KORIG;
    u16* dst = &As[((ts & 1) << 1) | mh][(srow << 6) + scol];
    const int mrow = m0 + (mh << 7) + srow;
#pragma unroll
    for (int j = 0; j < 2; ++j) {
      const int m = mrow + (j << 6);
      const u16* src;
      if (NTAPS == 1) {
        src = A + (size_t)m * KORIG + c0 + sx;
      } else {
        const int sp = (m & 1023) + tap - 1;
        src = ((unsigned)sp < 1024u) ? (A + (size_t)(m + tap - 1) * KORIG + c0 + sx)
                                     : (zp + ((tid & 255) << 3));
      }
      async16(src, dst + (j << 12));
    }
  };
  auto stageB = [&](int ts, int nh) {
    u16* dst = &Bs[((ts & 1) << 1) | nh][(srow << 6) + scol];
#pragma unroll
    for (int j = 0; j < 2; ++j) {
      async16(bp[nh][j], dst + (j << 12));
      bp[nh][j] += 64;
    }
  };

  f32x4 acc[2][4][2][2] = {};
  bf16x8 afC[4], afN[4], bfk[2][2][2];

  // prologue: stage all 4 halves of tile 0; then issue ph0's read-ahead (afC+bf[ks0])
  stageA(0, 0); stageB(0, 0); stageB(0, 1); stageA(0, 1);
  WAITV(0);
  BAR8();
  READ_AF(afC, 0, 0);
  READ_BF(0, 0);

#pragma unroll 2
  for (int t = 0; t < NT; ++t) {
    const int s = (t & 1) << 1;
    const bool pf = (t + 1 < NT);
    // ---- ph0 (mh0,ks0): stage t+1 burst; read-ahead afN(mh0,ks1)+bf[ks1] ----
    if (pf) { stageA(t + 1, 0); stageB(t + 1, 0); stageB(t + 1, 1); stageA(t + 1, 1); }
    READ_AF(afN, s | 0, 1);
    READ_BF(1, s);
    BAR8();
    LGKM(8); SB0();
    MFMA_P(0, afC, 0);
    // ---- ph1 (mh0,ks1): read-ahead afC(mh1,ks0) ----
    READ_AF(afC, s | 1, 0);
    BAR8();
    LGKM(4); SB0();
    MFMA_P(0, afN, 1);
    // ---- ph2 (mh1,ks0): read-ahead afN(mh1,ks1) ----
    READ_AF(afN, s | 1, 1);
    BAR8();
    LGKM(4); SB0();
    MFMA_P(1, afC, 0);
    WAITV(0);
    BAR8();                       // end-ph2: t+1 stages visible to all waves
    // ---- ph3 (mh1,ks1): read-ahead afC(t+1,mh0,ks0)+bf[ks0](t+1) ----
    if (pf) { READ_AF(afC, (s ^ 2) | 0, 0); READ_BF(0, s ^ 2); }
    BAR8();
    if (pf) { LGKM(8); } else { LGKM(0); }
    SB0();
    MFMA_P(1, afN, 1);
    BAR8();                       // end-ph3: t-1-slot reads drained before ph0(t+1) staging
  }

  // epilogue
  u16* dst = C;
  if (SPLITK > 1 && kz > 0) dst = Calt + (size_t)(kz - 1) * ((size_t)M * N);
#pragma unroll
  for (int mh = 0; mh < 2; ++mh)
#pragma unroll
    for (int nh = 0; nh < 2; ++nh)
#pragma unroll
      for (int ni = 0; ni < 2; ++ni) {
        const int col = n0 + (nh << 7) + wn + (ni << 4) + fr;
        const float bv = (SPLITK == 1 && bias) ? bias[col] : 0.f;
#pragma unroll
        for (int mi = 0; mi < 4; ++mi)
#pragma unroll
          for (int r = 0; r < 4; ++r) {
            float v = acc[mh][mi][nh][ni][r] + bv;
            if (RELU) v = fmaxf(v, 0.f);
            dst[(size_t)(m0 + (mh << 7) + wm + (mi << 4) + (quad << 2) + r) * N + col] = f2bf(v);
          }
      }
}

// ---------------- V^T gather: Vt[(bm*1024+ch)][512] = V[b, padIdx[mb][j], ch] ----------------
__global__ __launch_bounds__(256)
void gather_v(const u16* __restrict__ qkv, const int* __restrict__ padIdx,
              const int* __restrict__ padCnt, u16* __restrict__ Vt) {
  const int bm = blockIdx.x;          // 16: b*4+mb
  const int jt = blockIdx.y;          // 8
  const int b = bm >> 2, mb = bm & 3;
  const int npad = padCnt[mb];
  const int npadR = (npad + 63) & ~63;
  if (jt * 64 >= npadR) return;
  const int tid = threadIdx.x;
  __shared__ int rows[64];
  if (tid < 64) {
    const int j = jt * 64 + tid;
    const int jj = j < npad ? j : npad - 1;
    rows[tid] = padIdx[(mb << 10) + jj];
  }
  __shared__ u16 tile[64][72];
  for (int c = 0; c < 16; ++c) {
    const int ch0 = c << 6;
    __syncthreads();
#pragma unroll
    for (int p = 0; p < 2; ++p) {
      const int r = (tid >> 3) + (p << 5);
      const int ch = (tid & 7) << 3;
      const uint4 v = *(const uint4*)(qkv + (size_t)((b << 10) + rows[r]) * 3072 + 2048 + ch0 + ch);
      const u16* us = (const u16*)&v;
#pragma unroll
      for (int e = 0; e < 8; ++e) tile[r][ch + e] = us[e];
    }
    __syncthreads();
#pragma unroll
    for (int p = 0; p < 2; ++p) {
      const int r = (tid >> 3) + (p << 5);   // channel row within chunk
      const int jc = (tid & 7) << 3;
      u16 tmp[8];
#pragma unroll
      for (int e = 0; e < 8; ++e) tmp[e] = tile[jc + e][r];
      *(uint4*)(Vt + (size_t)((bm << 10) + ch0 + r) * 512 + jt * 64 + jc) = *(const uint4*)tmp;
    }
  }
}

// ---------------- MFMA flash attention over PAD keys (faithful to mask bug) ----------------
__global__ __launch_bounds__(256)
void attn_mfma(const u16* __restrict__ qkv, const u16* __restrict__ Vt,
               const int* __restrict__ padIdx, const int* __restrict__ padCnt,
               u16* __restrict__ vecS) {
  __shared__ __align__(16) u16 Ks[64 * 64];
  __shared__ __align__(16) u16 Vts[64 * 64];
  __shared__ __align__(16) u16 Ps[4][32 * 88];
  __shared__ int rowsIdx[512];
  const int i = blockIdx.x;     // 64
  const int qt = blockIdx.y;    // 8
  const int b = i >> 4, h = i & 15;
  const int mb = h & 3, bm = (b << 2) + mb;
  const int h_out = i >> 2;
  const int npad = padCnt[mb];
  const int nkt = (npad + 63) >> 6;
  const int tid = threadIdx.x;
  const int w = tid >> 6, lane = tid & 63;
  const int fr = lane & 15, quad = lane >> 4, fko = quad << 3;
  const int srow = tid >> 3, scol = (tid & 7) << 3;
  const int sx = (((tid & 7) ^ (srow & 7)) << 3);

#pragma unroll
  for (int p = 0; p < 2; ++p) {
    const int j = (p << 8) + tid;
    const int jj = j < npad ? j : npad - 1;
    rowsIdx[j] = padIdx[(mb << 10) + jj];
  }

  const int qw = (qt << 7) + (w << 5);
  bf16x8 qf[2][2];
#pragma unroll
  for (int rt = 0; rt < 2; ++rt)
#pragma unroll
    for (int ks = 0; ks < 2; ++ks)
      qf[rt][ks] = *(const bf16x8*)(qkv + (size_t)((b << 10) + qw + (rt << 4) + fr) * 3072 +
                                    (h << 6) + (ks << 5) + fko);

  f32x4 O[2][4];
  float mrun[2][4], lrun[2][4];
#pragma unroll
  for (int rt = 0; rt < 2; ++rt)
#pragma unroll
    for (int r = 0; r < 4; ++r) {
      mrun[rt][r] = -1e30f; lrun[rt][r] = 0.f;
#pragma unroll
      for (int dt = 0; dt < 4; ++dt) O[rt][dt][r] = 0.f;
    }
  __syncthreads();

  for (int kt = 0; kt < nkt; ++kt) {
#pragma unroll
    for (int p = 0; p < 2; ++p) {
      const int r = srow + (p << 5);
      const int grow = rowsIdx[(kt << 6) + r];
      async16(qkv + (size_t)((b << 10) + grow) * 3072 + 1024 + (h << 6) + sx,
              &Ks[(r << 6) + scol]);
      async16(Vt + (size_t)((bm << 10) + (h << 6) + r) * 512 + (kt << 6) + sx,
              &Vts[(r << 6) + scol]);
    }
    asm volatile("s_waitcnt vmcnt(0)" ::: "memory");
    __syncthreads();

    f32x4 S[2][4];
#pragma unroll
    for (int rt = 0; rt < 2; ++rt)
#pragma unroll
      for (int nt = 0; nt < 4; ++nt)
#pragma unroll
        for (int r = 0; r < 4; ++r) S[rt][nt][r] = 0.f;
#pragma unroll
    for (int ks = 0; ks < 2; ++ks) {
      const int ccol = ((((ks << 2) + quad) ^ (fr & 7)) << 3);
      bf16x8 bfr[4];
#pragma unroll
      for (int nt = 0; nt < 4; ++nt)
        bfr[nt] = *(const bf16x8*)&Ks[(((nt << 4) + fr) << 6) + ccol];
#pragma unroll
      for (int rt = 0; rt < 2; ++rt)
#pragma unroll
        for (int nt = 0; nt < 4; ++nt)
          S[rt][nt] = __builtin_amdgcn_mfma_f32_16x16x32_bf16(qf[rt][ks], bfr[nt], S[rt][nt], 0, 0, 0);
    }

#pragma unroll
    for (int nt = 0; nt < 4; ++nt) {
      const int key = (kt << 6) + (nt << 4) + fr;
      const bool dead = (key >= npad);
#pragma unroll
      for (int rt = 0; rt < 2; ++rt)
#pragma unroll
        for (int r = 0; r < 4; ++r) {
          float s = S[rt][nt][r] * 0.125f;
          S[rt][nt][r] = dead ? -1e30f : s;
        }
    }

#pragma unroll
    for (int rt = 0; rt < 2; ++rt) {
#pragma unroll
      for (int r = 0; r < 4; ++r) {
        float mx = fmaxf(fmaxf(S[rt][0][r], S[rt][1][r]), fmaxf(S[rt][2][r], S[rt][3][r]));
#pragma unroll
        for (int off = 1; off <= 8; off <<= 1) mx = fmaxf(mx, __shfl_xor(mx, off, 64));
        const float mnew = fmaxf(mrun[rt][r], mx);
        const float alpha = __expf(mrun[rt][r] - mnew);
        mrun[rt][r] = mnew;
        float rsum = 0.f;
#pragma unroll
        for (int nt = 0; nt < 4; ++nt) {
          const float p_ = __expf(S[rt][nt][r] - mnew);
          S[rt][nt][r] = p_;
          rsum += p_;
        }
#pragma unroll
        for (int off = 1; off <= 8; off <<= 1) rsum += __shfl_xor(rsum, off, 64);
        lrun[rt][r] = lrun[rt][r] * alpha + rsum;
#pragma unroll
        for (int dt = 0; dt < 4; ++dt) O[rt][dt][r] *= alpha;
      }
    }

    u16* ps = &Ps[w][0];
#pragma unroll
    for (int rt = 0; rt < 2; ++rt)
#pragma unroll
      for (int nt = 0; nt < 4; ++nt)
#pragma unroll
        for (int r = 0; r < 4; ++r)
          ps[((rt << 4) + (quad << 2) + r) * 88 + (nt << 4) + fr] = f2bf(S[rt][nt][r]);
    asm volatile("s_waitcnt lgkmcnt(0)" ::: "memory");

#pragma unroll
    for (int ks = 0; ks < 2; ++ks) {
      const int ccol = ((((ks << 2) + quad) ^ (fr & 7)) << 3);
      bf16x8 af[2], bv[4];
#pragma unroll
      for (int rt = 0; rt < 2; ++rt)
        af[rt] = *(const bf16x8*)&ps[((rt << 4) + fr) * 88 + (ks << 5) + fko];
#pragma unroll
      for (int dt = 0; dt < 4; ++dt)
        bv[dt] = *(const bf16x8*)&Vts[(((dt << 4) + fr) << 6) + ccol];
#pragma unroll
      for (int rt = 0; rt < 2; ++rt)
#pragma unroll
        for (int dt = 0; dt < 4; ++dt)
          O[rt][dt] = __builtin_amdgcn_mfma_f32_16x16x32_bf16(af[rt], bv[dt], O[rt][dt], 0, 0, 0);
    }
    __syncthreads();
  }

#pragma unroll
  for (int rt = 0; rt < 2; ++rt)
#pragma unroll
    for (int r = 0; r < 4; ++r) {
      const float inv = 1.f / lrun[rt][r];
      const int q = qw + (rt << 4) + (quad << 2) + r;
      u16* orow = vecS + (size_t)((mb << 10) + q) * 1024 + (h_out << 6);
#pragma unroll
      for (int dt = 0; dt < 4; ++dt)
        orow[(dt << 4) + fr] = f2bf(O[rt][dt][r] * inv);
    }
}

// ---------------- LN fused with split-K(4) reduce ----------------
template<bool XF32, bool OUTF32, bool HASB>
__global__ __launch_bounds__(256)
void ln_red4(const void* __restrict__ Xv, const u16* __restrict__ P0,
             const u16* __restrict__ P1, int MN,
             const float* __restrict__ bias,
             const float* __restrict__ g, const float* __restrict__ be,
             const float* __restrict__ maskf, void* __restrict__ outv) {
  const int r = blockIdx.x;
  const int tid = threadIdx.x;
  const size_t base = (size_t)r << 10;
  const float* Xf = (const float*)Xv;
  const u16* Xb = (const u16*)Xv;
  float x[4];
  float s1 = 0.f, s2 = 0.f;
#pragma unroll
  for (int j = 0; j < 4; ++j) {
    const int c = (tid << 2) + j;
    const size_t idx = base + c;
    float y = bf2f(P0[idx]) + bf2f(P1[idx]) + bf2f(P1[MN + idx]) + bf2f(P1[2 * (size_t)MN + idx]);
    if (HASB) y += bias[c];
    const float xv = XF32 ? Xf[idx] : bf2f(Xb[idx]);
    const float v = xv + y;
    x[j] = v; s1 += v; s2 += v * v;
  }
#pragma unroll
  for (int off = 32; off > 0; off >>= 1) { s1 += __shfl_xor(s1, off, 64); s2 += __shfl_xor(s2, off, 64); }
  __shared__ float rs1[4], rs2[4];
  if ((tid & 63) == 0) { rs1[tid >> 6] = s1; rs2[tid >> 6] = s2; }
  __syncthreads();
  s1 = rs1[0] + rs1[1] + rs1[2] + rs1[3];
  s2 = rs2[0] + rs2[1] + rs2[2] + rs2[3];
  const float mean = s1 * (1.f / 1024.f);
  const float var = s2 * (1.f / 1024.f) - mean * mean;
  const float rstd = rsqrtf(var + 1e-3f);
  const float mv = maskf[r];
#pragma unroll
  for (int j = 0; j < 4; ++j) {
    const int c = (tid << 2) + j;
    const float y = ((x[j] - mean) * rstd * g[c] + be[c]) * mv;
    if (OUTF32) ((float*)outv)[base + c] = y;
    else ((u16*)outv)[base + c] = f2bf(y);
  }
}

extern "C" void kernel_launch(void* const* d_in, const int* in_sizes, int n_in,
                              void* d_out, int out_size, void* d_ws, size_t ws_size,
                              hipStream_t stream) {
  (void)in_sizes; (void)n_in; (void)out_size; (void)ws_size;
  const float* dec  = (const float*)d_in[0];
  const unsigned char* mask = (const unsigned char*)d_in[1];
  const float* wqkv = (const float*)d_in[2];
  const float* bqkv = (const float*)d_in[3];
  const float* wo   = (const float*)d_in[4];
  const float* g1   = (const float*)d_in[5];
  const float* b1   = (const float*)d_in[6];
  const float* w1   = (const float*)d_in[7];
  const float* bc1  = (const float*)d_in[8];
  const float* w2   = (const float*)d_in[9];
  const float* bc2  = (const float*)d_in[10];
  const float* g2   = (const float*)d_in[11];
  const float* b2   = (const float*)d_in[12];
  char* ws = (char*)d_ws;
  u16*   zp    = (u16*)(ws + 0);
  int*   pcnt  = (int*)(ws + 16384);
  float* maskf = (float*)(ws + 20480);
  int*   pidx  = (int*)(ws + 40960);
  u16*   decB  = (u16*)(ws + 65536);
  u16*   wqkvT = (u16*)(ws + 8454144);
  u16*   woT   = (u16*)(ws + 14745600);
  u16*   w1T   = (u16*)(ws + 16842752);
  u16*   w2T   = (u16*)(ws + 42008576);
  u16*   qkv   = (u16*)(ws + 67174400);
  u16*   Vt    = (u16*)(ws + 92340224);
  u16*   vecS  = (u16*)(ws + 109117440);
  u16*   x1bf  = (u16*)(ws + 8454144);
  u16*   ybuf  = (u16*)(ws + 67174400);
  u16*   aP0   = (u16*)(ws + 65536);
  u16*   aP1   = (u16*)(ws + 67174400);
  u16*   cP0   = (u16*)(ws + 65536);
  u16*   cP1   = (u16*)(ws + 16842752);

  hipMemsetAsync(zp, 0, 16384, stream);
  compact_mask<<<dim3(4), dim3(64), 0, stream>>>(mask, pidx, pcnt, maskf);
  f32_to_bf16<<<dim3(4096), dim3(256), 0, stream>>>(dec, decB, 1048576);
  transpose_f32_bf16<<<dim3(48, 16), dim3(256), 0, stream>>>(wqkv, wqkvT, 1024, 3072);
  transpose_f32_bf16<<<dim3(16, 16), dim3(256), 0, stream>>>(wo, woT, 1024, 1024);
  transpose_f32_bf16<<<dim3(64, 48), dim3(256), 0, stream>>>(w1, w1T, 3072, 4096);
  transpose_f32_bf16<<<dim3(16, 192), dim3(256), 0, stream>>>(w2, w2T, 12288, 1024);
  // qkv = dec @ qkv_w + qkv_b   (256^2 tiles: 16x12 = 192 blocks)
  gemm8<1, false, 1, 1024><<<dim3(192), dim3(512), 0, stream>>>(decB, wqkvT, bqkv, qkv, nullptr, 4096, 3072, zp);
  // attention
  gather_v<<<dim3(16, 8), dim3(256), 0, stream>>>(qkv, pidx, pcnt, Vt);
  attn_mfma<<<dim3(64, 8), dim3(256), 0, stream>>>(qkv, Vt, pidx, pcnt, vecS);
  // attn_out partials = vecS @ o_w : split-K=4 (legacy 128^2 kernel, small GEMM)
  gemm_bt<1, false, 4, 1024, 8><<<dim3(8, 32, 4), dim3(256), 0, stream>>>(vecS, woT, nullptr, aP0, aP1, 4096, 1024, zp);
  // x1 = LN1(dec + sum(atto partials)) * mask
  ln_red4<true, false, false><<<dim3(4096), dim3(256), 0, stream>>>(dec, aP0, aP1, 4194304, nullptr, g1, b1, maskf, x1bf);
  // y = relu(conv1(x1))   (256^2 tiles: 16x16 = 256 blocks)
  gemm8<3, true, 1, 1024><<<dim3(256), dim3(512), 0, stream>>>(x1bf, w1T, bc1, ybuf, nullptr, 4096, 4096, zp);
  // core partials = conv2(y): split-K=4 (16x4 tiles x 4 = 256 blocks)
  gemm8<3, false, 4, 4096><<<dim3(64, 1, 4), dim3(512), 0, stream>>>(ybuf, w2T, nullptr, cP0, cP1, 4096, 1024, zp);
  // out = LN2(x1 + sum(partials)+bias) * mask -> fp32 d_out
  ln_red4<false, true, true><<<dim3(4096), dim3(256), 0, stream>>>(x1bf, cP0, cP1, 4194304, bc2, g2, b2, maskf, (float*)d_out);
}

// Round 4
// 476.352 us; speedup vs baseline: 1.3854x; 1.3854x over previous
//
#include <hip/hip_runtime.h>
#include <cstdint>
#include <cstddef>

typedef float f32x4 __attribute__((ext_vector_type(4)));
typedef __bf16 bf16x8 __attribute__((ext_vector_type(8)));
typedef unsigned short u16;

__device__ __forceinline__ float bf2f(u16 u) {
  union { unsigned int i; float f; } x; x.i = ((unsigned int)u) << 16; return x.f;
}
__device__ __forceinline__ u16 f2bf(float f) {
  union { float f; unsigned int i; } x; x.f = f;
  unsigned int i = x.i;
  i += 0x7fffu + ((i >> 16) & 1u);   // round-to-nearest-even
  return (u16)(i >> 16);
}

#if defined(__has_builtin)
#if __has_builtin(__builtin_amdgcn_global_load_lds)
#define HAS_GLL 1
#endif
#endif

__device__ __forceinline__ void async16(const u16* g, u16* l) {
#ifdef HAS_GLL
  __builtin_amdgcn_global_load_lds((const __attribute__((address_space(1))) void*)(const void*)g,
                                   (__attribute__((address_space(3))) void*)(void*)l, 16, 0, 0);
#else
  *(uint4*)l = *(const uint4*)g;
#endif
}

// ---------------- mask compaction (dtype-width-agnostic) ----------------
__global__ void compact_mask(const unsigned char* __restrict__ mask,
                             int* __restrict__ padIdx, int* __restrict__ padCnt,
                             float* __restrict__ maskf) {
  const int b = blockIdx.x;        // 4 rows
  const int lane = threadIdx.x;    // 64
  int stride = 1;
  if (mask[1] == 0) stride = (mask[4] != 0) ? 4 : 8;
  int cnt = 0;
  for (int s0 = 0; s0 < 1024; s0 += 64) {
    const int s = s0 + lane;
    const bool valid = (mask[(size_t)((b << 10) + s) * stride] != 0);
    maskf[(b << 10) + s] = valid ? 1.f : 0.f;
    const bool pad = !valid;
    const unsigned long long bal = __ballot(pad);
    const int rank = (int)__popcll(bal & ((1ull << lane) - 1ull));
    if (pad) padIdx[(b << 10) + cnt + rank] = s;
    cnt += (int)__popcll(bal);
  }
  if (lane == 0) padCnt[b] = cnt;
}

// ---------------- fp32 -> bf16 convert ----------------
__global__ __launch_bounds__(256)
void f32_to_bf16(const float* __restrict__ in, u16* __restrict__ out, int n4) {
  const int i = blockIdx.x * 256 + threadIdx.x;
  if (i < n4) {
    const float4 v = ((const float4*)in)[i];
    u16 o[4] = { f2bf(v.x), f2bf(v.y), f2bf(v.z), f2bf(v.w) };
    ((ushort4*)out)[i] = *(const ushort4*)o;
  }
}

// ---------------- fp32 transpose+convert: in[R][C] f32 -> out[C][R] bf16 ----------------
__global__ __launch_bounds__(256)
void transpose_f32_bf16(const float* __restrict__ in, u16* __restrict__ out, int R, int C) {
  __shared__ u16 tile[64][65];
  const int r0 = blockIdx.y << 6, c0 = blockIdx.x << 6;
  const int tid = threadIdx.x;
  const int lr = tid >> 3, lc = (tid & 7) << 3;
#pragma unroll
  for (int p = 0; p < 2; ++p) {
    const int row = lr + (p << 5);
    const float4 a = *(const float4*)(in + (size_t)(r0 + row) * C + c0 + lc);
    const float4 bq = *(const float4*)(in + (size_t)(r0 + row) * C + c0 + lc + 4);
    tile[row][lc + 0] = f2bf(a.x); tile[row][lc + 1] = f2bf(a.y);
    tile[row][lc + 2] = f2bf(a.z); tile[row][lc + 3] = f2bf(a.w);
    tile[row][lc + 4] = f2bf(bq.x); tile[row][lc + 5] = f2bf(bq.y);
    tile[row][lc + 6] = f2bf(bq.z); tile[row][lc + 7] = f2bf(bq.w);
  }
  __syncthreads();
#pragma unroll
  for (int p = 0; p < 2; ++p) {
    const int oc = lr + (p << 5);
    u16 tmp[8];
#pragma unroll
    for (int e = 0; e < 8; ++e) tmp[e] = tile[lc + e][oc];
    *(uint4*)(out + (size_t)(c0 + oc) * R + r0 + lc) = *(const uint4*)tmp;
  }
}

// ---------------- legacy 128x128 GEMM (kept for the small atto matmul) ----------------
template<int NTAPS, bool RELU, int SPLITK, int KORIG, int NBN>
__global__ __launch_bounds__(256)
void gemm_bt(const u16* __restrict__ A, const u16* __restrict__ BT,
             const float* __restrict__ bias, u16* __restrict__ C, u16* __restrict__ Calt,
             int M, int N, const u16* __restrict__ zp) {
  __shared__ __align__(16) u16 As[128 * 64];
  __shared__ __align__(16) u16 Bs[128 * 64];
  const int tid = threadIdx.x;
  const int id = blockIdx.x + NBN * blockIdx.y;
  const int bm = ((id / (16 * NBN)) << 4) + (id & 15);
  const int bn = (id % (16 * NBN)) >> 4;
  const int m0 = bm << 7;
  const int n0 = bn << 7;
  const int kz = (SPLITK > 1) ? blockIdx.z : 0;
  constexpr int Ktot = NTAPS * KORIG;
  constexpr int kchunk = Ktot / SPLITK;
  const int lane = tid & 63;
  const int w = tid >> 6;
  const int wm = (w >> 1) << 6;
  const int wn = (w & 1) << 6;
  const int fr = lane & 15;
  const int quad = lane >> 4;
  const int srow = tid >> 3;
  const int scol = (tid & 7) << 3;
  const int sx = (((tid & 7) ^ (srow & 7)) << 3);

  f32x4 acc[4][4] = {};

  const int kbeg = kz * kchunk, kend = kbeg + kchunk;
  int k = kbeg;
  while (k < kend) {
    const int t = (NTAPS == 3) ? (k / KORIG) : 0;
    const int seg_end = (NTAPS == 3) ? min(kend, (t + 1) * KORIG) : kend;
    const int c0 = k - t * KORIG;
    const u16* aptr[4];
    const u16* bptr[4];
#pragma unroll
    for (int i = 0; i < 4; ++i) {
      const int row = srow + (i << 5);
      if (NTAPS == 3) {
        const int m = m0 + row;
        const int sp = (m & 1023) + t - 1;
        aptr[i] = ((unsigned)sp < 1024u) ? (A + (size_t)(m + t - 1) * KORIG + c0 + sx)
                                         : (zp + ((tid & 255) << 3));
      } else {
        aptr[i] = A + (size_t)(m0 + row) * KORIG + k + sx;
      }
      bptr[i] = BT + (size_t)(n0 + row) * Ktot + k + sx;
    }
    for (; k < seg_end; k += 64) {
#pragma unroll
      for (int i = 0; i < 4; ++i) {
        const int row = srow + (i << 5);
        async16(aptr[i], &As[(row << 6) + scol]);
        async16(bptr[i], &Bs[(row << 6) + scol]);
        aptr[i] += 64; bptr[i] += 64;
      }
      asm volatile("s_waitcnt vmcnt(0)" ::: "memory");
      __syncthreads();
#pragma unroll
      for (int ks = 0; ks < 64; ks += 32) {
        const int ccol = ((((ks >> 3) + quad) ^ (fr & 7)) << 3);
        bf16x8 af[4], bfr[4];
#pragma unroll
        for (int mi = 0; mi < 4; ++mi)
          af[mi] = *(const bf16x8*)&As[((wm + (mi << 4) + fr) << 6) + ccol];
#pragma unroll
        for (int ni = 0; ni < 4; ++ni)
          bfr[ni] = *(const bf16x8*)&Bs[((wn + (ni << 4) + fr) << 6) + ccol];
#pragma unroll
        for (int mi = 0; mi < 4; ++mi)
#pragma unroll
          for (int ni = 0; ni < 4; ++ni)
            acc[mi][ni] = __builtin_amdgcn_mfma_f32_16x16x32_bf16(af[mi], bfr[ni], acc[mi][ni], 0, 0, 0);
      }
      __syncthreads();
    }
  }
  const int rbase = m0 + wm + (quad << 2);
  const int cbase = n0 + wn + fr;
  u16* dst = C;
  if (SPLITK > 1 && kz > 0) dst = Calt + (size_t)(kz - 1) * ((size_t)M * N);
#pragma unroll
  for (int ni = 0; ni < 4; ++ni) {
    const int col = cbase + (ni << 4);
    const float bv = (SPLITK == 1 && bias) ? bias[col] : 0.f;
#pragma unroll
    for (int mi = 0; mi < 4; ++mi) {
#pragma unroll
      for (int r = 0; r < 4; ++r) {
        float v = acc[mi][ni][r] + bv;
        if (RELU) v = fmaxf(v, 0.f);
        dst[(size_t)(rbase + (mi << 4) + r) * N + col] = f2bf(v);
      }
    }
  }
}

// ---------------- 256x256 GEMM, depth-2 half-tile ring (T3+T4+T5, m201-style) ----------------
// 8 waves (2M x 4N), BK=64. LDS = 2 banks x {A0,A1,B0,B1} half-slots (128x64 each).
// Quadrant phases (mh,nh): (0,0)->(0,1)->(1,1)->(1,0); reads 12/4/8/0 per phase.
// DEPTH-2 staging: during tile t, stage tile t+2 into the SAME bank being consumed,
// each half right after its last read (ph1: A0+B0, ph2: B1, ph3: A1). Stage->consume
// distance ~7 phases. ONE counted WAITV(8) per tile (at ph3) retires ALL of t+1's 8
// loads; t+2's 8 stay in flight across the tile boundary (T4 counted-vmcnt).
// Per-phase {reads; LGKM(0); BAR} guarantees a slot's reads are drained block-wide
// before the next phase's stage-issue can overwrite it.
// Ledger: invariant entering ph0(t): queue=[t+1's 8], t's all retired. During t: +8
// (t+2). WAITV(8)@ph3 retires t+1's 8, leaves t+2's 8. Prologue stages tiles 0 and 1
// (16 loads), WAITV(8). Boundary: t>=NT-2 skips staging, WAITV(0).
#define BAR8() do { asm volatile("" ::: "memory"); __builtin_amdgcn_s_barrier(); asm volatile("" ::: "memory"); } while (0)
#define WAITV(N) asm volatile("s_waitcnt vmcnt(" #N ")" ::: "memory")
#define LGKM0() asm volatile("s_waitcnt lgkmcnt(0)" ::: "memory")

#define READ_A(SLOT) \
  _Pragma("unroll") for (int mi = 0; mi < 4; ++mi) \
  _Pragma("unroll") for (int ks = 0; ks < 2; ++ks) \
    af[mi][ks] = *(const bf16x8*)&As[SLOT][((wm + (mi << 4) + fr) << 6) + ((((ks << 2) + quad) ^ (fr & 7)) << 3)];
#define READ_B(SLOT, BFR) \
  _Pragma("unroll") for (int ni = 0; ni < 2; ++ni) \
  _Pragma("unroll") for (int ks = 0; ks < 2; ++ks) \
    BFR[ni][ks] = *(const bf16x8*)&Bs[SLOT][((wn + (ni << 4) + fr) << 6) + ((((ks << 2) + quad) ^ (fr & 7)) << 3)];
#define MFMA_PH(MH, NH, BFR) \
  __builtin_amdgcn_s_setprio(1); \
  _Pragma("unroll") for (int mi = 0; mi < 4; ++mi) \
  _Pragma("unroll") for (int ni = 0; ni < 2; ++ni) \
  _Pragma("unroll") for (int ks = 0; ks < 2; ++ks) \
    acc[MH][mi][NH][ni] = __builtin_amdgcn_mfma_f32_16x16x32_bf16(af[mi][ks], BFR[ni][ks], acc[MH][mi][NH][ni], 0, 0, 0); \
  __builtin_amdgcn_s_setprio(0)

template<int NTAPS, bool RELU, int SPLITK, int KORIG>
__global__ __launch_bounds__(512, 2)
void gemm8(const u16* __restrict__ A, const u16* __restrict__ BT,
           const float* __restrict__ bias, u16* __restrict__ C, u16* __restrict__ Calt,
           int M, int N, const u16* __restrict__ zp) {
  __shared__ __align__(16) u16 As[4][128 * 64];   // 64 KB: banks {t&1} x halves {mh}
  __shared__ __align__(16) u16 Bs[4][128 * 64];   // 64 KB
  constexpr int Ktot = NTAPS * KORIG;
  constexpr int kchunk = Ktot / SPLITK;
  constexpr int NT = kchunk / 64;
  const int tid = threadIdx.x;
  const int id = blockIdx.x;
  const int bm = id & 15, bn = id >> 4;
  const int m0 = bm << 8, n0 = bn << 8;
  const int kz = (SPLITK > 1) ? blockIdx.z : 0;
  const int kbeg = kz * kchunk;
  const int lane = tid & 63, w = tid >> 6;
  const int wm = (w >> 2) << 6;       // within-half M base (0/64)
  const int wn = (w & 3) << 5;        // within-half N base (0/32/64/96)
  const int fr = lane & 15, quad = lane >> 4;
  const int srow = tid >> 3;          // 0..63
  const int scol = (tid & 7) << 3;    // linear LDS dest col (dest = base + 16B*lane)
  const int sx = (((tid & 7) ^ (srow & 7)) << 3);   // swizzled global src col

  // persistent B staging pointers (advance +64/stage call)
  const u16* bp[2][2];
#pragma unroll
  for (int nh = 0; nh < 2; ++nh)
#pragma unroll
    for (int j = 0; j < 2; ++j)
      bp[nh][j] = BT + (size_t)(n0 + (nh << 7) + srow + (j << 6)) * Ktot + kbeg + sx;

  auto stageA = [&](int ts, int mh) {
    const int k = kbeg + (ts << 6);
    const int tap = (NTAPS == 3) ? (k / KORIG) : 0;
    const int c0 = k - tap * KORIG;
    u16* dst = &As[((ts & 1) << 1) | mh][(srow << 6) + scol];
    const int mrow = m0 + (mh << 7) + srow;
#pragma unroll
    for (int j = 0; j < 2; ++j) {
      const int m = mrow + (j << 6);
      const u16* src;
      if (NTAPS == 1) {
        src = A + (size_t)m * KORIG + c0 + sx;
      } else {
        const int sp = (m & 1023) + tap - 1;
        src = ((unsigned)sp < 1024u) ? (A + (size_t)(m + tap - 1) * KORIG + c0 + sx)
                                     : (zp + ((tid & 255) << 3));
      }
      async16(src, dst + (j << 12));
    }
  };
  auto stageB = [&](int ts, int nh) {
    u16* dst = &Bs[((ts & 1) << 1) | nh][(srow << 6) + scol];
#pragma unroll
    for (int j = 0; j < 2; ++j) {
      async16(bp[nh][j], dst + (j << 12));
      bp[nh][j] += 64;
    }
  };

  f32x4 acc[2][4][2][2] = {};
  bf16x8 af[4][2], bf0[2][2], bf1[2][2];

  // prologue: stage tiles 0 AND 1 (depth-2); retire tile 0's 8, keep tile 1's 8 in flight
  stageA(0, 0); stageB(0, 0); stageB(0, 1); stageA(0, 1);
  if (NT > 1) {
    stageA(1, 0); stageB(1, 0); stageB(1, 1); stageA(1, 1);
    WAITV(8);
  } else {
    WAITV(0);
  }
  BAR8();

#pragma unroll 2
  for (int t = 0; t < NT; ++t) {
    const int s = (t & 1) << 1;
    const bool pf2 = (t + 2 < NT);
    // ---- phase 0: (mh0, nh0) ---- reads A0+B0 (last reads of those slots this tile)
    READ_A(s | 0);
    READ_B(s | 0, bf0);
    LGKM0();
    BAR8();
    MFMA_PH(0, 0, bf0);
    // ---- phase 1: (mh0, nh1) ---- A0/B0 slots now free -> stage t+2's A0,B0
    if (pf2) { stageA(t + 2, 0); stageB(t + 2, 0); }
    READ_B(s | 1, bf1);
    LGKM0();
    BAR8();
    MFMA_PH(0, 1, bf1);
    // ---- phase 2: (mh1, nh1) ---- B1 slot free -> stage t+2's B1
    if (pf2) stageB(t + 2, 1);
    READ_A(s | 1);
    LGKM0();
    BAR8();
    MFMA_PH(1, 1, bf1);
    // ---- phase 3: (mh1, nh0) ---- A1 slot free -> stage t+2's A1; single counted wait
    if (pf2) { stageA(t + 2, 1); WAITV(8); } else { WAITV(0); }
    BAR8();
    MFMA_PH(1, 0, bf0);
  }

  // epilogue
  u16* dst = C;
  if (SPLITK > 1 && kz > 0) dst = Calt + (size_t)(kz - 1) * ((size_t)M * N);
#pragma unroll
  for (int mh = 0; mh < 2; ++mh)
#pragma unroll
    for (int nh = 0; nh < 2; ++nh)
#pragma unroll
      for (int ni = 0; ni < 2; ++ni) {
        const int col = n0 + (nh << 7) + wn + (ni << 4) + fr;
        const float bv = (SPLITK == 1 && bias) ? bias[col] : 0.f;
#pragma unroll
        for (int mi = 0; mi < 4; ++mi)
#pragma unroll
          for (int r = 0; r < 4; ++r) {
            float v = acc[mh][mi][nh][ni][r] + bv;
            if (RELU) v = fmaxf(v, 0.f);
            dst[(size_t)(m0 + (mh << 7) + wm + (mi << 4) + (quad << 2) + r) * N + col] = f2bf(v);
          }
      }
}

// ---------------- V^T gather: Vt[(bm*1024+ch)][512] = V[b, padIdx[mb][j], ch] ----------------
__global__ __launch_bounds__(256)
void gather_v(const u16* __restrict__ qkv, const int* __restrict__ padIdx,
              const int* __restrict__ padCnt, u16* __restrict__ Vt) {
  const int bm = blockIdx.x;          // 16: b*4+mb
  const int jt = blockIdx.y;          // 8
  const int b = bm >> 2, mb = bm & 3;
  const int npad = padCnt[mb];
  const int npadR = (npad + 63) & ~63;
  if (jt * 64 >= npadR) return;
  const int tid = threadIdx.x;
  __shared__ int rows[64];
  if (tid < 64) {
    const int j = jt * 64 + tid;
    const int jj = j < npad ? j : npad - 1;
    rows[tid] = padIdx[(mb << 10) + jj];
  }
  __shared__ u16 tile[64][72];
  for (int c = 0; c < 16; ++c) {
    const int ch0 = c << 6;
    __syncthreads();
#pragma unroll
    for (int p = 0; p < 2; ++p) {
      const int r = (tid >> 3) + (p << 5);
      const int ch = (tid & 7) << 3;
      const uint4 v = *(const uint4*)(qkv + (size_t)((b << 10) + rows[r]) * 3072 + 2048 + ch0 + ch);
      const u16* us = (const u16*)&v;
#pragma unroll
      for (int e = 0; e < 8; ++e) tile[r][ch + e] = us[e];
    }
    __syncthreads();
#pragma unroll
    for (int p = 0; p < 2; ++p) {
      const int r = (tid >> 3) + (p << 5);   // channel row within chunk
      const int jc = (tid & 7) << 3;
      u16 tmp[8];
#pragma unroll
      for (int e = 0; e < 8; ++e) tmp[e] = tile[jc + e][r];
      *(uint4*)(Vt + (size_t)((bm << 10) + ch0 + r) * 512 + jt * 64 + jc) = *(const uint4*)tmp;
    }
  }
}

// ---------------- MFMA flash attention over PAD keys (faithful to mask bug) ----------------
__global__ __launch_bounds__(256)
void attn_mfma(const u16* __restrict__ qkv, const u16* __restrict__ Vt,
               const int* __restrict__ padIdx, const int* __restrict__ padCnt,
               u16* __restrict__ vecS) {
  __shared__ __align__(16) u16 Ks[64 * 64];
  __shared__ __align__(16) u16 Vts[64 * 64];
  __shared__ __align__(16) u16 Ps[4][32 * 88];
  __shared__ int rowsIdx[512];
  const int i = blockIdx.x;     // 64
  const int qt = blockIdx.y;    // 8
  const int b = i >> 4, h = i & 15;
  const int mb = h & 3, bm = (b << 2) + mb;
  const int h_out = i >> 2;
  const int npad = padCnt[mb];
  const int nkt = (npad + 63) >> 6;
  const int tid = threadIdx.x;
  const int w = tid >> 6, lane = tid & 63;
  const int fr = lane & 15, quad = lane >> 4, fko = quad << 3;
  const int srow = tid >> 3, scol = (tid & 7) << 3;
  const int sx = (((tid & 7) ^ (srow & 7)) << 3);

#pragma unroll
  for (int p = 0; p < 2; ++p) {
    const int j = (p << 8) + tid;
    const int jj = j < npad ? j : npad - 1;
    rowsIdx[j] = padIdx[(mb << 10) + jj];
  }

  const int qw = (qt << 7) + (w << 5);
  bf16x8 qf[2][2];
#pragma unroll
  for (int rt = 0; rt < 2; ++rt)
#pragma unroll
    for (int ks = 0; ks < 2; ++ks)
      qf[rt][ks] = *(const bf16x8*)(qkv + (size_t)((b << 10) + qw + (rt << 4) + fr) * 3072 +
                                    (h << 6) + (ks << 5) + fko);

  f32x4 O[2][4];
  float mrun[2][4], lrun[2][4];
#pragma unroll
  for (int rt = 0; rt < 2; ++rt)
#pragma unroll
    for (int r = 0; r < 4; ++r) {
      mrun[rt][r] = -1e30f; lrun[rt][r] = 0.f;
#pragma unroll
      for (int dt = 0; dt < 4; ++dt) O[rt][dt][r] = 0.f;
    }
  __syncthreads();

  for (int kt = 0; kt < nkt; ++kt) {
#pragma unroll
    for (int p = 0; p < 2; ++p) {
      const int r = srow + (p << 5);
      const int grow = rowsIdx[(kt << 6) + r];
      async16(qkv + (size_t)((b << 10) + grow) * 3072 + 1024 + (h << 6) + sx,
              &Ks[(r << 6) + scol]);
      async16(Vt + (size_t)((bm << 10) + (h << 6) + r) * 512 + (kt << 6) + sx,
              &Vts[(r << 6) + scol]);
    }
    asm volatile("s_waitcnt vmcnt(0)" ::: "memory");
    __syncthreads();

    f32x4 S[2][4];
#pragma unroll
    for (int rt = 0; rt < 2; ++rt)
#pragma unroll
      for (int nt = 0; nt < 4; ++nt)
#pragma unroll
        for (int r = 0; r < 4; ++r) S[rt][nt][r] = 0.f;
#pragma unroll
    for (int ks = 0; ks < 2; ++ks) {
      const int ccol = ((((ks << 2) + quad) ^ (fr & 7)) << 3);
      bf16x8 bfr[4];
#pragma unroll
      for (int nt = 0; nt < 4; ++nt)
        bfr[nt] = *(const bf16x8*)&Ks[(((nt << 4) + fr) << 6) + ccol];
#pragma unroll
      for (int rt = 0; rt < 2; ++rt)
#pragma unroll
        for (int nt = 0; nt < 4; ++nt)
          S[rt][nt] = __builtin_amdgcn_mfma_f32_16x16x32_bf16(qf[rt][ks], bfr[nt], S[rt][nt], 0, 0, 0);
    }

#pragma unroll
    for (int nt = 0; nt < 4; ++nt) {
      const int key = (kt << 6) + (nt << 4) + fr;
      const bool dead = (key >= npad);
#pragma unroll
      for (int rt = 0; rt < 2; ++rt)
#pragma unroll
        for (int r = 0; r < 4; ++r) {
          float s = S[rt][nt][r] * 0.125f;
          S[rt][nt][r] = dead ? -1e30f : s;
        }
    }

#pragma unroll
    for (int rt = 0; rt < 2; ++rt) {
#pragma unroll
      for (int r = 0; r < 4; ++r) {
        float mx = fmaxf(fmaxf(S[rt][0][r], S[rt][1][r]), fmaxf(S[rt][2][r], S[rt][3][r]));
#pragma unroll
        for (int off = 1; off <= 8; off <<= 1) mx = fmaxf(mx, __shfl_xor(mx, off, 64));
        const float mnew = fmaxf(mrun[rt][r], mx);
        const float alpha = __expf(mrun[rt][r] - mnew);
        mrun[rt][r] = mnew;
        float rsum = 0.f;
#pragma unroll
        for (int nt = 0; nt < 4; ++nt) {
          const float p_ = __expf(S[rt][nt][r] - mnew);
          S[rt][nt][r] = p_;
          rsum += p_;
        }
#pragma unroll
        for (int off = 1; off <= 8; off <<= 1) rsum += __shfl_xor(rsum, off, 64);
        lrun[rt][r] = lrun[rt][r] * alpha + rsum;
#pragma unroll
        for (int dt = 0; dt < 4; ++dt) O[rt][dt][r] *= alpha;
      }
    }

    u16* ps = &Ps[w][0];
#pragma unroll
    for (int rt = 0; rt < 2; ++rt)
#pragma unroll
      for (int nt = 0; nt < 4; ++nt)
#pragma unroll
        for (int r = 0; r < 4; ++r)
          ps[((rt << 4) + (quad << 2) + r) * 88 + (nt << 4) + fr] = f2bf(S[rt][nt][r]);
    asm volatile("s_waitcnt lgkmcnt(0)" ::: "memory");

#pragma unroll
    for (int ks = 0; ks < 2; ++ks) {
      const int ccol = ((((ks << 2) + quad) ^ (fr & 7)) << 3);
      bf16x8 af[2], bv[4];
#pragma unroll
      for (int rt = 0; rt < 2; ++rt)
        af[rt] = *(const bf16x8*)&ps[((rt << 4) + fr) * 88 + (ks << 5) + fko];
#pragma unroll
      for (int dt = 0; dt < 4; ++dt)
        bv[dt] = *(const bf16x8*)&Vts[(((dt << 4) + fr) << 6) + ccol];
#pragma unroll
      for (int rt = 0; rt < 2; ++rt)
#pragma unroll
        for (int dt = 0; dt < 4; ++dt)
          O[rt][dt] = __builtin_amdgcn_mfma_f32_16x16x32_bf16(af[rt], bv[dt], O[rt][dt], 0, 0, 0);
    }
    __syncthreads();
  }

#pragma unroll
  for (int rt = 0; rt < 2; ++rt)
#pragma unroll
    for (int r = 0; r < 4; ++r) {
      const float inv = 1.f / lrun[rt][r];
      const int q = qw + (rt << 4) + (quad << 2) + r;
      u16* orow = vecS + (size_t)((mb << 10) + q) * 1024 + (h_out << 6);
#pragma unroll
      for (int dt = 0; dt < 4; ++dt)
        orow[(dt << 4) + fr] = f2bf(O[rt][dt][r] * inv);
    }
}

// ---------------- LN fused with split-K(4) reduce ----------------
template<bool XF32, bool OUTF32, bool HASB>
__global__ __launch_bounds__(256)
void ln_red4(const void* __restrict__ Xv, const u16* __restrict__ P0,
             const u16* __restrict__ P1, int MN,
             const float* __restrict__ bias,
             const float* __restrict__ g, const float* __restrict__ be,
             const float* __restrict__ maskf, void* __restrict__ outv) {
  const int r = blockIdx.x;
  const int tid = threadIdx.x;
  const size_t base = (size_t)r << 10;
  const float* Xf = (const float*)Xv;
  const u16* Xb = (const u16*)Xv;
  float x[4];
  float s1 = 0.f, s2 = 0.f;
#pragma unroll
  for (int j = 0; j < 4; ++j) {
    const int c = (tid << 2) + j;
    const size_t idx = base + c;
    float y = bf2f(P0[idx]) + bf2f(P1[idx]) + bf2f(P1[MN + idx]) + bf2f(P1[2 * (size_t)MN + idx]);
    if (HASB) y += bias[c];
    const float xv = XF32 ? Xf[idx] : bf2f(Xb[idx]);
    const float v = xv + y;
    x[j] = v; s1 += v; s2 += v * v;
  }
#pragma unroll
  for (int off = 32; off > 0; off >>= 1) { s1 += __shfl_xor(s1, off, 64); s2 += __shfl_xor(s2, off, 64); }
  __shared__ float rs1[4], rs2[4];
  if ((tid & 63) == 0) { rs1[tid >> 6] = s1; rs2[tid >> 6] = s2; }
  __syncthreads();
  s1 = rs1[0] + rs1[1] + rs1[2] + rs1[3];
  s2 = rs2[0] + rs2[1] + rs2[2] + rs2[3];
  const float mean = s1 * (1.f / 1024.f);
  const float var = s2 * (1.f / 1024.f) - mean * mean;
  const float rstd = rsqrtf(var + 1e-3f);
  const float mv = maskf[r];
#pragma unroll
  for (int j = 0; j < 4; ++j) {
    const int c = (tid << 2) + j;
    const float y = ((x[j] - mean) * rstd * g[c] + be[c]) * mv;
    if (OUTF32) ((float*)outv)[base + c] = y;
    else ((u16*)outv)[base + c] = f2bf(y);
  }
}

extern "C" void kernel_launch(void* const* d_in, const int* in_sizes, int n_in,
                              void* d_out, int out_size, void* d_ws, size_t ws_size,
                              hipStream_t stream) {
  (void)in_sizes; (void)n_in; (void)out_size; (void)ws_size;
  const float* dec  = (const float*)d_in[0];
  const unsigned char* mask = (const unsigned char*)d_in[1];
  const float* wqkv = (const float*)d_in[2];
  const float* bqkv = (const float*)d_in[3];
  const float* wo   = (const float*)d_in[4];
  const float* g1   = (const float*)d_in[5];
  const float* b1   = (const float*)d_in[6];
  const float* w1   = (const float*)d_in[7];
  const float* bc1  = (const float*)d_in[8];
  const float* w2   = (const float*)d_in[9];
  const float* bc2  = (const float*)d_in[10];
  const float* g2   = (const float*)d_in[11];
  const float* b2   = (const float*)d_in[12];
  char* ws = (char*)d_ws;
  u16*   zp    = (u16*)(ws + 0);
  int*   pcnt  = (int*)(ws + 16384);
  float* maskf = (float*)(ws + 20480);
  int*   pidx  = (int*)(ws + 40960);
  u16*   decB  = (u16*)(ws + 65536);
  u16*   wqkvT = (u16*)(ws + 8454144);
  u16*   woT   = (u16*)(ws + 14745600);
  u16*   w1T   = (u16*)(ws + 16842752);
  u16*   w2T   = (u16*)(ws + 42008576);
  u16*   qkv   = (u16*)(ws + 67174400);
  u16*   Vt    = (u16*)(ws + 92340224);
  u16*   vecS  = (u16*)(ws + 109117440);
  u16*   x1bf  = (u16*)(ws + 8454144);
  u16*   ybuf  = (u16*)(ws + 67174400);
  u16*   aP0   = (u16*)(ws + 65536);
  u16*   aP1   = (u16*)(ws + 67174400);
  u16*   cP0   = (u16*)(ws + 65536);
  u16*   cP1   = (u16*)(ws + 16842752);

  hipMemsetAsync(zp, 0, 16384, stream);
  compact_mask<<<dim3(4), dim3(64), 0, stream>>>(mask, pidx, pcnt, maskf);
  f32_to_bf16<<<dim3(4096), dim3(256), 0, stream>>>(dec, decB, 1048576);
  transpose_f32_bf16<<<dim3(48, 16), dim3(256), 0, stream>>>(wqkv, wqkvT, 1024, 3072);
  transpose_f32_bf16<<<dim3(16, 16), dim3(256), 0, stream>>>(wo, woT, 1024, 1024);
  transpose_f32_bf16<<<dim3(64, 48), dim3(256), 0, stream>>>(w1, w1T, 3072, 4096);
  transpose_f32_bf16<<<dim3(16, 192), dim3(256), 0, stream>>>(w2, w2T, 12288, 1024);
  // qkv = dec @ qkv_w + qkv_b   (256^2 tiles: 16x12 = 192 blocks)
  gemm8<1, false, 1, 1024><<<dim3(192), dim3(512), 0, stream>>>(decB, wqkvT, bqkv, qkv, nullptr, 4096, 3072, zp);
  // attention
  gather_v<<<dim3(16, 8), dim3(256), 0, stream>>>(qkv, pidx, pcnt, Vt);
  attn_mfma<<<dim3(64, 8), dim3(256), 0, stream>>>(qkv, Vt, pidx, pcnt, vecS);
  // attn_out partials = vecS @ o_w : split-K=4 (legacy 128^2 kernel, small GEMM)
  gemm_bt<1, false, 4, 1024, 8><<<dim3(8, 32, 4), dim3(256), 0, stream>>>(vecS, woT, nullptr, aP0, aP1, 4096, 1024, zp);
  // x1 = LN1(dec + sum(atto partials)) * mask
  ln_red4<true, false, false><<<dim3(4096), dim3(256), 0, stream>>>(dec, aP0, aP1, 4194304, nullptr, g1, b1, maskf, x1bf);
  // y = relu(conv1(x1))   (256^2 tiles: 16x16 = 256 blocks)
  gemm8<3, true, 1, 1024><<<dim3(256), dim3(512), 0, stream>>>(x1bf, w1T, bc1, ybuf, nullptr, 4096, 4096, zp);
  // core partials = conv2(y): split-K=4 (16x4 tiles x 4 = 256 blocks)
  gemm8<3, false, 4, 4096><<<dim3(64, 1, 4), dim3(512), 0, stream>>>(ybuf, w2T, nullptr, cP0, cP1, 4096, 1024, zp);
  // out = LN2(x1 + sum(partials)+bias) * mask -> fp32 d_out
  ln_red4<false, true, true><<<dim3(4096), dim3(256), 0, stream>>>(x1bf, cP0, cP1, 4194304, bc2, g2, b2, maskf, (float*)d_out);
}